// Round 3
// baseline (641.999 us; speedup 1.0000x reference)
//
#include <hip/hip_runtime.h>

// ---------------------------------------------------------------------------
// GAT encoder: x --GATConv(2 heads,128)--> ELU --> {GATConv mu, GATConv ls}
// N=50000, E=800000 (+self loops). ALL float inputs/outputs are fp32 per the
// reference (prior rounds' bf16 reads of fp32 buffers were the NaN source).
// Edges: int32 per harness contract, with device-side int64 auto-detect.
// CSR by dst built once per call; atomic-free aggregation (1 wave / dst node).
// x1 scratch (fp32 [n,256]) lives in d_out; h in ws (fp32, bf16 fallback).
// ---------------------------------------------------------------------------

typedef unsigned short u16;
typedef unsigned int u32;

__device__ __forceinline__ void unpack2(u32 u, float& lo, float& hi) {
    union { u32 i; float f; } a, b;
    a.i = u << 16; b.i = u & 0xffff0000u;
    lo = a.f; hi = b.f;
}
__device__ __forceinline__ u16 f2b(float f) {  // RNE float->bf16
    union { float f; u32 i; } v; v.f = f;
    u32 x = v.i;
    return (u16)((x + 0x7fffu + ((x >> 16) & 1u)) >> 16);
}
__device__ __forceinline__ float4 loadh4(const float* __restrict__ p, size_t i) {
    return *(const float4*)(p + i);
}
__device__ __forceinline__ float4 loadh4(const u16* __restrict__ p, size_t i) {
    uint2 u = *(const uint2*)(p + i);
    float4 r;
    unpack2(u.x, r.x, r.y);
    unpack2(u.y, r.z, r.w);
    return r;
}
__device__ __forceinline__ void storeh4(float* __restrict__ p, size_t i, float4 v) {
    *(float4*)(p + i) = v;
}
__device__ __forceinline__ void storeh4(u16* __restrict__ p, size_t i, float4 v) {
    uint2 pk = make_uint2((u32)f2b(v.x) | ((u32)f2b(v.y) << 16),
                          (u32)f2b(v.z) | ((u32)f2b(v.w) << 16));
    *(uint2*)(p + i) = pk;
}

// ---------------- edge dtype detect + normalize ----------------
// int64 edges (values < 2^32) have every odd u32 word == 0.
__global__ __launch_bounds__(256) void k_detect(const u32* __restrict__ ebuf,
                                                int* __restrict__ flag) {
    __shared__ int nz;
    if (threadIdx.x == 0) nz = 0;
    __syncthreads();
    if (ebuf[2 * threadIdx.x + 1] != 0u) atomicAdd(&nz, 1);
    __syncthreads();
    if (threadIdx.x == 0) *flag = (nz == 0) ? 1 : 0;
}

__global__ __launch_bounds__(256) void k_extract(const u32* __restrict__ ebuf, int E,
                                                 const int* __restrict__ flag,
                                                 int* __restrict__ se,
                                                 int* __restrict__ de) {
    int e = blockIdx.x * 256 + threadIdx.x;
    if (e >= E) return;
    if (*flag) {  // int64 layout
        se[e] = (int)ebuf[2 * (size_t)e];
        de[e] = (int)ebuf[2 * ((size_t)E + (size_t)e)];
    } else {  // int32 layout
        se[e] = (int)ebuf[e];
        de[e] = (int)ebuf[(size_t)E + (size_t)e];
    }
}

// ---------------- CSR build ----------------
__global__ __launch_bounds__(256) void k_count(const int* __restrict__ dst, int E,
                                               int* __restrict__ deg) {
    int e = blockIdx.x * 256 + threadIdx.x;
    if (e < E) atomicAdd(&deg[dst[e]], 1);
}

__global__ __launch_bounds__(256) void k_scan_a(const int* __restrict__ deg, int n,
                                                int* __restrict__ bsum) {
    __shared__ int s[256];
    int i = blockIdx.x * 256 + threadIdx.x;
    s[threadIdx.x] = (i < n) ? deg[i] : 0;
    __syncthreads();
    for (int st = 128; st > 0; st >>= 1) {
        if (threadIdx.x < st) s[threadIdx.x] += s[threadIdx.x + st];
        __syncthreads();
    }
    if (threadIdx.x == 0) bsum[blockIdx.x] = s[0];
}

__global__ __launch_bounds__(256) void k_scan_b(int* __restrict__ bsum, int nb) {
    __shared__ int s[256];
    int t = threadIdx.x;
    int v = (t < nb) ? bsum[t] : 0;
    s[t] = v;
    __syncthreads();
    for (int off = 1; off < 256; off <<= 1) {
        int add = (t >= off) ? s[t - off] : 0;
        __syncthreads();
        s[t] += add;
        __syncthreads();
    }
    if (t < nb) bsum[t] = s[t] - v;  // exclusive
}

__global__ __launch_bounds__(256) void k_scan_c(const int* __restrict__ deg, int n,
                                                const int* __restrict__ bsum,
                                                int* __restrict__ rowptr,
                                                int* __restrict__ cursor, int E) {
    __shared__ int s[256];
    int t = threadIdx.x;
    int i = blockIdx.x * 256 + t;
    int v = (i < n) ? deg[i] : 0;
    s[t] = v;
    __syncthreads();
    for (int off = 1; off < 256; off <<= 1) {
        int add = (t >= off) ? s[t - off] : 0;
        __syncthreads();
        s[t] += add;
        __syncthreads();
    }
    if (i < n) {
        int ex = bsum[blockIdx.x] + s[t] - v;
        rowptr[i] = ex;
        cursor[i] = ex;
    }
    if (i == 0) rowptr[n] = E;
}

__global__ __launch_bounds__(256) void k_fill(const int* __restrict__ src,
                                              const int* __restrict__ dst, int E,
                                              int* __restrict__ cursor,
                                              int* __restrict__ csr_src) {
    int e = blockIdx.x * 256 + threadIdx.x;
    if (e < E) {
        int d = dst[e];
        int slot = atomicAdd(&cursor[d], 1);
        csr_src[slot] = src[e];
    }
}

// ---------------- GEMM: out[M,256] = A[M,K](f32) @ W[K,256](f32) ------------
// split==256: single W (row stride 256). split==128: cols 0..127 from Wl,
// 128..255 from Wr (row stride 128 each). 256 thr; 32-row x 256-col tile;
// each thread 8 rows x 4 cols; K staged in 16-row chunks.
template <int K, typename OT>
__global__ __launch_bounds__(256) void k_gemm(const float* __restrict__ A,
                                              const float* __restrict__ Wl,
                                              const float* __restrict__ Wr, int split,
                                              OT* __restrict__ out, int M) {
    __shared__ float As[32 * K];     // 16KB (K=128) / 32KB (K=256)
    __shared__ float Ws[16 * 256];   // 16KB
    const int tid = threadIdx.x;
    const int row0 = blockIdx.x * 32;

    for (int ch = tid; ch < 32 * K / 4; ch += 256) {
        int flat = ch * 4;
        int r = flat / K, k = flat % K;
        float4 val = make_float4(0.f, 0.f, 0.f, 0.f);
        if (row0 + r < M) val = *(const float4*)(A + (size_t)(row0 + r) * K + k);
        *(float4*)(&As[flat]) = val;
    }

    float acc[8][4];
#pragma unroll
    for (int r = 0; r < 8; r++)
#pragma unroll
        for (int c = 0; c < 4; c++) acc[r][c] = 0.f;

    const int cg = (tid & 63) * 4;
    const int rg = (tid >> 6) * 8;

    for (int kc = 0; kc < K; kc += 16) {
        __syncthreads();  // A staged (first iter) / prior chunk's compute done
        for (int ch = tid; ch < 16 * 256 / 4; ch += 256) {
            int flat = ch * 4;
            int k = flat >> 8, c = flat & 255;
            const float* wp;
            if (split == 256)
                wp = Wl + (size_t)(kc + k) * 256 + c;
            else
                wp = (c < 128) ? Wl + (size_t)(kc + k) * 128 + c
                               : Wr + (size_t)(kc + k) * 128 + (c - 128);
            *(float4*)(&Ws[flat]) = *(const float4*)wp;
        }
        __syncthreads();
#pragma unroll
        for (int k8 = 0; k8 < 16; k8 += 8) {
            float wv[8][4];
#pragma unroll
            for (int j = 0; j < 8; j++)
                *(float4*)wv[j] = *(const float4*)(&Ws[(k8 + j) * 256 + cg]);
#pragma unroll
            for (int r = 0; r < 8; r++) {
                float av[8];
                *(float4*)(av) = *(const float4*)(&As[(rg + r) * K + kc + k8]);
                *(float4*)(av + 4) = *(const float4*)(&As[(rg + r) * K + kc + k8 + 4]);
#pragma unroll
                for (int j = 0; j < 8; j++)
#pragma unroll
                    for (int c = 0; c < 4; c++) acc[r][c] += av[j] * wv[j][c];
            }
        }
    }

#pragma unroll
    for (int r = 0; r < 8; r++) {
        int row = row0 + rg + r;
        if (row < M)
            storeh4(out, (size_t)row * 256 + cg,
                    make_float4(acc[r][0], acc[r][1], acc[r][2], acc[r][3]));
    }
}

// ---------------- attention logits: as/ad[n,NS] ------------------------------
// One wave per node; lane l owns channels 4l..4l+3 of h[n,256].
// LOGW=5: 2 slots of 128 ch (layer 1). LOGW=4: 4 slots of 64 ch (mu|ls).
template <int LOGW, typename HT>
__global__ __launch_bounds__(256) void k_alphas(const HT* __restrict__ h,
                                                const float* __restrict__ as_lo,
                                                const float* __restrict__ as_hi,
                                                const float* __restrict__ ad_lo,
                                                const float* __restrict__ ad_hi,
                                                float* __restrict__ as_out,
                                                float* __restrict__ ad_out, int n) {
    const int W = 1 << LOGW;
    const int NS = 64 >> LOGW;
    int wid = blockIdx.x * 4 + (threadIdx.x >> 6);
    int lane = threadIdx.x & 63;
    if (wid >= n) return;
    int c = lane * 4;
    int ci = c & 127;
    const float* ap = (c < 128) ? as_lo : as_hi;
    const float* dp = (c < 128) ? ad_lo : ad_hi;
    float4 hv = loadh4(h, (size_t)wid * 256 + c);
    float4 av = *(const float4*)(ap + ci);
    float4 dv = *(const float4*)(dp + ci);
    float ssum = hv.x * av.x + hv.y * av.y + hv.z * av.z + hv.w * av.w;
    float dsum = hv.x * dv.x + hv.y * dv.y + hv.z * dv.z + hv.w * dv.w;
#pragma unroll
    for (int m = W / 2; m >= 1; m >>= 1) {
        ssum += __shfl_xor(ssum, m, 64);
        dsum += __shfl_xor(dsum, m, 64);
    }
    if ((lane & (W - 1)) == 0) {
        int slot = lane >> LOGW;
        as_out[(size_t)wid * NS + slot] = ssum;
        ad_out[(size_t)wid * NS + slot] = dsum;
    }
}

// ---------------- aggregation (softmax-weighted gather) ----------------------
// One wave per dst node; lane owns 4 channels; self-loop folded in.
// MODE 0: +bias, ELU, write fp32 x1 [n,256]. MODE 1: +bias, write mu/ls.
template <int LOGW, int MODE, typename HT>
__global__ __launch_bounds__(256) void k_agg(const HT* __restrict__ h,
                                             const int* __restrict__ rowptr,
                                             const int* __restrict__ csr_src,
                                             const float* __restrict__ as,
                                             const float* __restrict__ ad,
                                             const float* __restrict__ b_lo,
                                             const float* __restrict__ b_hi,
                                             float* __restrict__ outp, int n) {
    const int NS = 64 >> LOGW;
    int wid = blockIdx.x * 4 + (threadIdx.x >> 6);
    int lane = threadIdx.x & 63;
    if (wid >= n) return;
    int slot = lane >> LOGW;
    int c = lane * 4;

    float adv = ad[(size_t)wid * NS + slot];
    float e = as[(size_t)wid * NS + slot] + adv;  // self-loop
    e = fmaxf(e, 0.2f * e);                       // LeakyReLU(0.2)
    float w = __expf(e);
    float denom = w;
    float4 hv = loadh4(h, (size_t)wid * 256 + c);
    float acc0 = w * hv.x, acc1 = w * hv.y, acc2 = w * hv.z, acc3 = w * hv.w;

    int rb = rowptr[wid], re = rowptr[wid + 1];
    for (int p = rb; p < re; ++p) {
        int s = csr_src[p];
        float ev = as[(size_t)s * NS + slot] + adv;
        ev = fmaxf(ev, 0.2f * ev);
        float ww = __expf(ev);
        denom += ww;
        float4 hh = loadh4(h, (size_t)s * 256 + c);
        acc0 += ww * hh.x;
        acc1 += ww * hh.y;
        acc2 += ww * hh.z;
        acc3 += ww * hh.w;
    }
    float inv = 1.0f / (denom + 1e-16f);

    int ci = c & 127;
    const float* bp = (c < 128) ? b_lo : b_hi;
    float4 bv = *(const float4*)(bp + ci);
    float v0 = acc0 * inv + bv.x;
    float v1 = acc1 * inv + bv.y;
    float v2 = acc2 * inv + bv.z;
    float v3 = acc3 * inv + bv.w;

    if (MODE == 0) {  // ELU -> x1 fp32 [n,256]
        v0 = v0 > 0.f ? v0 : expm1f(v0);
        v1 = v1 > 0.f ? v1 : expm1f(v1);
        v2 = v2 > 0.f ? v2 : expm1f(v2);
        v3 = v3 > 0.f ? v3 : expm1f(v3);
        *(float4*)(&outp[(size_t)wid * 256 + c]) = make_float4(v0, v1, v2, v3);
    } else {  // mu (c<128) then logstd, each [n,128] fp32, concatenated
        size_t base = (c < 128) ? ((size_t)wid * 128 + c)
                                : ((size_t)n * 128 + (size_t)wid * 128 + (c - 128));
        *(float4*)(&outp[base]) = make_float4(v0, v1, v2, v3);
    }
}

// ---------------------------------------------------------------------------
extern "C" void kernel_launch(void* const* d_in, const int* in_sizes, int n_in,
                              void* d_out, int out_size, void* d_ws, size_t ws_size,
                              hipStream_t stream) {
    const float* x = (const float*)d_in[0];
    const u32* ebuf = (const u32*)d_in[1];
    const float* W1 = (const float*)d_in[2];
    const float* a_src1 = (const float*)d_in[3];
    const float* a_dst1 = (const float*)d_in[4];
    const float* b1 = (const float*)d_in[5];
    const float* W_mu = (const float*)d_in[6];
    const float* a_src_mu = (const float*)d_in[7];
    const float* a_dst_mu = (const float*)d_in[8];
    const float* b_mu = (const float*)d_in[9];
    const float* W_ls = (const float*)d_in[10];
    const float* a_src_ls = (const float*)d_in[11];
    const float* a_dst_ls = (const float*)d_in[12];
    const float* b_ls = (const float*)d_in[13];

    const int n = in_sizes[0] / 128;  // 50000
    const int E = in_sizes[1] / 2;    // 800000

    char* base = (char*)d_ws;
    size_t off = 0;
    auto alloc = [&](size_t b) -> char* {
        char* p = base + off;
        off = (off + b + 255) & ~(size_t)255;
        return p;
    };
    int* rowptr = (int*)alloc((size_t)(n + 1) * 4);
    int* cursor = (int*)alloc((size_t)n * 4);
    int* csr = (int*)alloc((size_t)E * 4);
    int* bsum = (int*)alloc(256 * 4);
    int* eflag = (int*)alloc(256);
    int* se = (int*)alloc((size_t)E * 4);
    int* de = (int*)alloc((size_t)E * 4);
    float* as = (float*)alloc((size_t)n * 4 * 4);
    float* ad = (float*)alloc((size_t)n * 4 * 4);
    char* hraw = alloc(0);  // h last; fp32 if it fits, else bf16
    bool hf32 = (off + (size_t)n * 256 * 4) <= ws_size;
    float* hf = (float*)hraw;
    u16* hb = (u16*)hraw;
    float* x1 = (float*)d_out;  // n*256 fp32 == 51.2MB == exactly d_out's size

    const int nb = (n + 255) / 256;
    const int eg = (E + 255) / 256;
    const int ng4 = (n + 3) / 4;
    const int gg = (n + 31) / 32;

    // edge normalize + CSR build (reused by all three convs)
    k_detect<<<1, 256, 0, stream>>>(ebuf, eflag);
    k_extract<<<eg, 256, 0, stream>>>(ebuf, E, eflag, se, de);
    hipMemsetAsync(cursor, 0, (size_t)n * 4, stream);
    k_count<<<eg, 256, 0, stream>>>(de, E, cursor);
    k_scan_a<<<nb, 256, 0, stream>>>(cursor, n, bsum);
    k_scan_b<<<1, 256, 0, stream>>>(bsum, nb);
    k_scan_c<<<nb, 256, 0, stream>>>(cursor, n, bsum, rowptr, cursor, E);
    k_fill<<<eg, 256, 0, stream>>>(se, de, E, cursor, csr);

    if (hf32) {
        k_gemm<128, float><<<gg, 256, 0, stream>>>(x, W1, W1, 256, hf, n);
        k_alphas<5, float><<<ng4, 256, 0, stream>>>(hf, a_src1, a_src1 + 128, a_dst1,
                                                    a_dst1 + 128, as, ad, n);
        k_agg<5, 0, float><<<ng4, 256, 0, stream>>>(hf, rowptr, csr, as, ad, b1,
                                                    b1 + 128, x1, n);
        k_gemm<256, float><<<gg, 256, 0, stream>>>(x1, W_mu, W_ls, 128, hf, n);
        k_alphas<4, float><<<ng4, 256, 0, stream>>>(hf, a_src_mu, a_src_ls, a_dst_mu,
                                                    a_dst_ls, as, ad, n);
        k_agg<4, 1, float><<<ng4, 256, 0, stream>>>(hf, rowptr, csr, as, ad, b_mu,
                                                    b_ls, (float*)d_out, n);
    } else {
        k_gemm<128, u16><<<gg, 256, 0, stream>>>(x, W1, W1, 256, hb, n);
        k_alphas<5, u16><<<ng4, 256, 0, stream>>>(hb, a_src1, a_src1 + 128, a_dst1,
                                                  a_dst1 + 128, as, ad, n);
        k_agg<5, 0, u16><<<ng4, 256, 0, stream>>>(hb, rowptr, csr, as, ad, b1,
                                                  b1 + 128, x1, n);
        k_gemm<256, u16><<<gg, 256, 0, stream>>>(x1, W_mu, W_ls, 128, hb, n);
        k_alphas<4, u16><<<ng4, 256, 0, stream>>>(hb, a_src_mu, a_src_ls, a_dst_mu,
                                                  a_dst_ls, as, ad, n);
        k_agg<4, 1, u16><<<ng4, 256, 0, stream>>>(hb, rowptr, csr, as, ad, b_mu,
                                                  b_ls, (float*)d_out, n);
    }
}